// Round 5
// baseline (718.589 us; speedup 1.0000x reference)
//
#include <hip/hip_runtime.h>
#include <stdint.h>

#define N_NODES 20000
#define N_EDGES 320000

typedef __attribute__((ext_vector_type(8)))  __bf16        bf16x8;
typedef __attribute__((ext_vector_type(16))) float         f32x16;
typedef __attribute__((ext_vector_type(4)))  float         f32x4v;
typedef __attribute__((ext_vector_type(8)))  unsigned short us8;
typedef __attribute__((ext_vector_type(4)))  unsigned short us4;
typedef __attribute__((ext_vector_type(2)))  unsigned short us2;

static __device__ __forceinline__ unsigned short cvt_bf16(float f) {
  uint32_t u = __builtin_bit_cast(uint32_t, f);
  u = (u + 0x7fffu + ((u >> 16) & 1u)) >> 16;
  return (unsigned short)u;
}
static __device__ __forceinline__ float cvt_f32(unsigned short h) {
  uint32_t u = ((uint32_t)h) << 16;
  return __builtin_bit_cast(float, u);
}

// async global->LDS, 16B per lane; LDS dest = wave-uniform base (HW adds lane*16)
static __device__ __forceinline__ void gll16(const void* g, void* l) {
  __builtin_amdgcn_global_load_lds(
      (const __attribute__((address_space(1))) unsigned int*)g,
      (__attribute__((address_space(3))) unsigned int*)l, 16, 0, 0);
}

// ---------------------------------------------------------------------------
// Pack row-major f32 W[K][Ncols] into MFMA A/B fragment order (bf16).
// out[((ks*(Ncols/32)+nt)*64+lane)*8+e] = W[ks*16+(lane>>5)*8+e][nt*32+(lane&31)]
// (verified R1-R4)
// ---------------------------------------------------------------------------
__global__ void pack_w(const float* __restrict__ W, unsigned short* __restrict__ out,
                       int K, int Ncols) {
  int idx = blockIdx.x * 256 + threadIdx.x;
  int total = K * Ncols;
  if (idx >= total) return;
  int e    = idx & 7;
  int lane = (idx >> 3) & 63;
  int t    = idx >> 9;
  int ntiles = Ncols >> 5;
  int nt = t % ntiles;
  int ks = t / ntiles;
  int k = ks * 16 + (lane >> 5) * 8 + e;
  int c = nt * 32 + (lane & 31);
  out[idx] = cvt_bf16(W[(size_t)k * Ncols + c]);
}

// ---------------------------------------------------------------------------
// CSR build for segment_sum (receivers constant across iterations)
// ---------------------------------------------------------------------------
__global__ void hist_k(const int* __restrict__ recv, int* __restrict__ cnt, int n) {
  int i = blockIdx.x * 256 + threadIdx.x;
  if (i < n) atomicAdd(&cnt[recv[i]], 1);
}

__global__ void scan_k(const int* __restrict__ cnt, int* __restrict__ off,
                       int* __restrict__ cursor, int n) {
  __shared__ int part[1024];
  int t = threadIdx.x;
  int chunk = (n + 1023) / 1024;
  int base = t * chunk;
  int s = 0;
  for (int i = 0; i < chunk; ++i) { int idx = base + i; if (idx < n) s += cnt[idx]; }
  part[t] = s;
  __syncthreads();
  for (int d = 1; d < 1024; d <<= 1) {
    int v = (t >= d) ? part[t - d] : 0;
    __syncthreads();
    part[t] += v;
    __syncthreads();
  }
  int prefix = (t > 0) ? part[t - 1] : 0;
  for (int i = 0; i < chunk; ++i) {
    int idx = base + i;
    if (idx < n) { off[idx] = prefix; cursor[idx] = prefix; prefix += cnt[idx]; }
  }
  if (t == 1023) off[n] = part[1023];
}

__global__ void fill_k(const int* __restrict__ recv, int* __restrict__ cursor,
                       int* __restrict__ eid, int n) {
  int i = blockIdx.x * 256 + threadIdx.x;
  if (i < n) {
    int p = atomicAdd(&cursor[recv[i]], 1);
    eid[p] = i;
  }
}

// agg[n][:] = sum_{edges -> n} e[edge][:], f32 accumulate, bf16 out
__global__ void agg_k(const unsigned short* __restrict__ eb, const int* __restrict__ off,
                      const int* __restrict__ eid, unsigned short* __restrict__ aggb, int n) {
  int node = blockIdx.x * 4 + (threadIdx.x >> 6);
  if (node >= n) return;
  int lane = threadIdx.x & 63;
  float a0 = 0.f, a1 = 0.f;
  int s = off[node], t = off[node + 1];
  for (int q = s; q < t; ++q) {
    int ei = eid[q];
    us2 v = *(const us2*)(eb + (size_t)ei * 128 + lane * 2);
    a0 += cvt_f32(v[0]);
    a1 += cvt_f32(v[1]);
  }
  us2 r; r[0] = cvt_bf16(a0); r[1] = cvt_bf16(a1);
  *(us2*)(aggb + (size_t)node * 128 + lane * 2) = r;
}

// ---------------------------------------------------------------------------
// Fused 2-layer MLP: out = relu(relu(A@W1+b1)@W2+b2), hidden 256, out 128.
// 128 rows/block, 256 thr (4 waves), 2 blocks/CU (LDS exactly 80 KB).
//   MODE 0: A = srcf (f32, reg-staged, __syncthreads path)
//   MODE 1: A = [x[snd], x[rcv], e]  bf16 (KIN=384, coalesced 4-rows/gll gather)
//   MODE 2: A = [x, agg]             bf16 (KIN=256)
// Layer 1 flipped (D1^T = W1f @ A^T); wave-tile 128hid x 64rows.
// LDS: [0,64K) = L1 stage 2 x (rows 8K @b*24576 + W1 16K @+8192), aliased with
//      Hs [32 pages][128 rows][16B]; [64K,80K) = W2 dbuf 2x8K (pool aliases).
// Rows tile: row-major [128][64B], chunk swizzle c^(row&3) applied on global
// source AND read side (both-sides rule); counted vmcnt, issue-1-ahead.
// ---------------------------------------------------------------------------
template <int KIN, int MODE, int POOL>
__global__ __launch_bounds__(256, 2)
void mlp_kernel(const float* __restrict__ srcf,
                const unsigned short* __restrict__ xb,
                const unsigned short* __restrict__ ebuf,
                const unsigned short* __restrict__ aggb,
                const int* __restrict__ senders,
                const int* __restrict__ receivers,
                const unsigned short* __restrict__ P1,
                const float* __restrict__ b1,
                const unsigned short* __restrict__ P2,
                const float* __restrict__ b2,
                unsigned short* __restrict__ dst,
                float* __restrict__ pool_out,
                int nrows) {
  constexpr int NS1 = KIN / 32;
  __shared__ __align__(16) unsigned char lds[81920];

  const int tid  = threadIdx.x;
  const int lane = tid & 63;
  const int wid  = tid >> 6;     // 0..3
  const int g    = lane >> 5;
  const int l31  = lane & 31;
  const int rowBlock = blockIdx.x << 7;   // 128 rows/block

  const int wm = wid >> 1;   // hid half (L1) / out-col half (L2)
  const int wq = wid & 1;    // row half

  const unsigned char* P1b = (const unsigned char*)P1;
  const unsigned char* P2b = (const unsigned char*)P2;

  // ---------------- stage identity ----------------
  const unsigned short *g0a=nullptr,*g0b=nullptr,*g0c=nullptr;
  const unsigned short *g1a=nullptr,*g1b=nullptr,*g1c=nullptr;
  int co = 0;
  const float* fb = nullptr; int r0 = 0, h0 = 0;
  if constexpr (MODE == 0) {
    r0 = tid >> 1; h0 = tid & 1;
    int gr = rowBlock + r0; if (gr >= nrows) gr = nrows - 1;
    fb = srcf + (size_t)gr * KIN;
  } else {
    const int rl0 = wid * 32 + (lane >> 2);   // gather row (j=0); j=1 is +16
    co = ((lane & 3) ^ (rl0 & 3)) * 8;        // swizzled chunk offset (shorts)
    int gr0 = rowBlock + rl0;      if (gr0 >= nrows) gr0 = nrows - 1;
    int gr1 = rowBlock + rl0 + 16; if (gr1 >= nrows) gr1 = nrows - 1;
    if constexpr (MODE == 1) {
      g0a = xb + (size_t)senders[gr0] * 128; g0b = xb + (size_t)receivers[gr0] * 128;
      g0c = ebuf + (size_t)gr0 * 128;
      g1a = xb + (size_t)senders[gr1] * 128; g1b = xb + (size_t)receivers[gr1] * 128;
      g1c = ebuf + (size_t)gr1 * 128;
    } else {
      g0a = xb + (size_t)gr0 * 128; g0b = aggb + (size_t)gr0 * 128;
      g1a = xb + (size_t)gr1 * 128; g1b = aggb + (size_t)gr1 * 128;
    }
  }

  // stage rows+W1 for step s into buf (s&1): 6 glls/wave (2 rows + 4 W1)
  auto STG1 = [&](int s) {
    unsigned char* bR = lds + (s & 1) * 24576;
    unsigned char* bW = bR + 8192;
    const int ko = (s * 32) & 127;
    const unsigned short *s0, *s1;
    const int seg = (s * 32) >> 7;
    if constexpr (MODE == 1) {
      s0 = (seg == 0) ? g0a : (seg == 1) ? g0b : g0c;
      s1 = (seg == 0) ? g1a : (seg == 1) ? g1b : g1c;
    } else {
      s0 = seg ? g0b : g0a;
      s1 = seg ? g1b : g1a;
    }
    gll16(s0 + ko + co, bR + wid * 2048);
    gll16(s1 + ko + co, bR + wid * 2048 + 1024);
#pragma unroll
    for (int c = 0; c < 4; ++c)
      gll16(P1b + (size_t)s * 16384 + wid * 4096 + c * 1024 + (size_t)lane * 16,
            bW + wid * 4096 + c * 1024);
  };

  // MODE 0: reg-staged rows (T14 split) + W1 gll, __syncthreads pipeline
  f32x4v pA0, pA1, pB0, pB1;
  auto LD0 = [&](int s) {
    const float* p = fb + s * 32 + h0 * 16;
    pA0 = *(const f32x4v*)(p);     pA1 = *(const f32x4v*)(p + 4);
    pB0 = *(const f32x4v*)(p + 8); pB1 = *(const f32x4v*)(p + 12);
  };
  auto WR0 = [&](int s) {
    unsigned char* bR = lds + (s & 1) * 24576;
    us8 ha, hb;
#pragma unroll
    for (int e = 0; e < 4; ++e) {
      ha[e] = cvt_bf16(pA0[e]); ha[4 + e] = cvt_bf16(pA1[e]);
      hb[e] = cvt_bf16(pB0[e]); hb[4 + e] = cvt_bf16(pB1[e]);
    }
    const int c0 = (h0 * 2) ^ (r0 & 3), c1 = (h0 * 2 + 1) ^ (r0 & 3);
    *(us8*)(bR + r0 * 64 + c0 * 16) = ha;
    *(us8*)(bR + r0 * 64 + c1 * 16) = hb;
  };
  auto STG1W0 = [&](int s) {
    unsigned char* bW = lds + (s & 1) * 24576 + 8192;
#pragma unroll
    for (int c = 0; c < 4; ++c)
      gll16(P1b + (size_t)s * 16384 + wid * 4096 + c * 1024 + (size_t)lane * 16,
            bW + wid * 4096 + c * 1024);
  };

  // ================= layer 1 =================
  f32x16 acc1[4][2];
#pragma unroll
  for (int mt = 0; mt < 4; ++mt)
#pragma unroll
    for (int q = 0; q < 2; ++q)
#pragma unroll
      for (int k = 0; k < 16; ++k) acc1[mt][q][k] = 0.0f;

  auto L1STEP = [&](int b) {
    const unsigned char* bR = lds + b * 24576;
    const unsigned char* bW = bR + 8192;
    bf16x8 af[2][4], br[2][2];
#pragma unroll
    for (int kc = 0; kc < 2; ++kc) {
#pragma unroll
      for (int mt = 0; mt < 4; ++mt)
        af[kc][mt] = __builtin_bit_cast(bf16x8,
            *(const us8*)(bW + kc * 8192 + (wm * 4 + mt) * 1024 + lane * 16));
#pragma unroll
      for (int q = 0; q < 2; ++q) {
        const int n = wq * 64 + q * 32 + l31;
        br[kc][q] = __builtin_bit_cast(bf16x8,
            *(const us8*)(bR + n * 64 + (((kc * 2 + g) ^ (n & 3)) * 16)));
      }
    }
#pragma unroll
    for (int kc = 0; kc < 2; ++kc)
#pragma unroll
      for (int mt = 0; mt < 4; ++mt)
#pragma unroll
        for (int q = 0; q < 2; ++q)
          acc1[mt][q] = __builtin_amdgcn_mfma_f32_32x32x16_bf16(
              af[kc][mt], br[kc][q], acc1[mt][q], 0, 0, 0);
  };

  if constexpr (MODE == 0) {
    LD0(0); WR0(0); STG1W0(0);
    if (NS1 > 1) LD0(1);
    __syncthreads();
#pragma unroll 1
    for (int s = 0; s < NS1; ++s) {
      if (s + 1 < NS1) STG1W0(s + 1);
      L1STEP(s & 1);
      if (s + 1 < NS1) {
        WR0(s + 1);
        if (s + 2 < NS1) LD0(s + 2);
      }
      __syncthreads();
    }
  } else {
    STG1(0);
#pragma unroll 1
    for (int s = 0; s < NS1; ++s) {
      if (s + 1 < NS1) {
        STG1(s + 1);
        asm volatile("s_waitcnt vmcnt(6)" ::: "memory");
      } else {
        asm volatile("s_waitcnt vmcnt(0)" ::: "memory");
      }
      asm volatile("s_barrier" ::: "memory");
      L1STEP(s & 1);
      asm volatile("s_waitcnt lgkmcnt(0)" ::: "memory");
      asm volatile("s_barrier" ::: "memory");
    }
  }

  // prefetch first W2 chunk (separate LDS region, stays in flight)
  auto STG2 = [&](int s) {
    unsigned char* bW2 = lds + 65536 + (s & 1) * 8192;
#pragma unroll
    for (int c = 0; c < 2; ++c)
      gll16(P2b + (size_t)s * 8192 + wid * 2048 + c * 1024 + (size_t)lane * 16,
            bW2 + wid * 2048 + c * 1024);
  };
  STG2(0);

  // layer-1 epilogue: bias+relu -> Hs [32 pages][128 rows][16B] (aliases stage)
#pragma unroll
  for (int mt = 0; mt < 4; ++mt) {
#pragma unroll
    for (int q = 0; q < 2; ++q) {
      const int j = wq * 64 + q * 32 + l31;
#pragma unroll
      for (int rq = 0; rq < 4; ++rq) {
        const int i0 = wm * 128 + mt * 32 + rq * 8 + g * 4;
        const f32x4v bb = *(const f32x4v*)(b1 + i0);
        us4 h;
#pragma unroll
        for (int e = 0; e < 4; ++e)
          h[e] = cvt_bf16(fmaxf(acc1[mt][q][rq * 4 + e] + bb[e], 0.0f));
        *(us4*)(lds + (i0 >> 3) * 2048 + j * 16 + g * 8) = h;
      }
    }
  }
  asm volatile("s_waitcnt lgkmcnt(0)" ::: "memory");
  asm volatile("s_barrier" ::: "memory");

  // ================= layer 2 =================
  f32x16 acc2[2][2];
#pragma unroll
  for (int q = 0; q < 2; ++q)
#pragma unroll
    for (int nt = 0; nt < 2; ++nt)
#pragma unroll
      for (int k = 0; k < 16; ++k) acc2[q][nt][k] = 0.0f;

#pragma unroll 1
  for (int s = 0; s < 8; ++s) {
    if (s + 1 < 8) {
      STG2(s + 1);
      asm volatile("s_waitcnt vmcnt(2)" ::: "memory");
    } else {
      asm volatile("s_waitcnt vmcnt(0)" ::: "memory");
    }
    asm volatile("s_barrier" ::: "memory");
    const unsigned char* bW2 = lds + 65536 + (s & 1) * 8192;
    bf16x8 ah[2][2], bw[2][2];
#pragma unroll
    for (int kc = 0; kc < 2; ++kc) {
#pragma unroll
      for (int q = 0; q < 2; ++q)
        ah[kc][q] = __builtin_bit_cast(bf16x8,
            *(const us8*)(lds + (size_t)(s * 4 + kc * 2 + g) * 2048 +
                          (wq * 64 + q * 32 + l31) * 16));
#pragma unroll
      for (int nt = 0; nt < 2; ++nt)
        bw[kc][nt] = __builtin_bit_cast(bf16x8,
            *(const us8*)(bW2 + kc * 4096 + (wm * 2 + nt) * 1024 + lane * 16));
    }
#pragma unroll
    for (int kc = 0; kc < 2; ++kc)
#pragma unroll
      for (int q = 0; q < 2; ++q)
#pragma unroll
        for (int nt = 0; nt < 2; ++nt)
          acc2[q][nt] = __builtin_amdgcn_mfma_f32_32x32x16_bf16(
              ah[kc][q], bw[kc][nt], acc2[q][nt], 0, 0, 0);
    asm volatile("s_waitcnt lgkmcnt(0)" ::: "memory");
    asm volatile("s_barrier" ::: "memory");
  }

  // layer-2 epilogue: bias+relu, bf16 store (+ fused pool partials)
  float* Ps = (float*)(lds + 65536);   // [2][128]; W2 region dead
#pragma unroll
  for (int q = 0; q < 2; ++q) {
    const float bias0 = b2[wm * 64 + l31];
    const float bias1 = b2[wm * 64 + 32 + l31];
#pragma unroll
    for (int reg = 0; reg < 16; ++reg) {
      const int rloc = wq * 64 + q * 32 + (reg & 3) + ((reg >> 2) << 3) + g * 4;
      const int row = rowBlock + rloc;
      float v0 = fmaxf(acc2[q][0][reg] + bias0, 0.0f);
      float v1 = fmaxf(acc2[q][1][reg] + bias1, 0.0f);
      if (row < nrows) {
        dst[(size_t)row * 128 + wm * 64 + l31]      = cvt_bf16(v0);
        dst[(size_t)row * 128 + wm * 64 + 32 + l31] = cvt_bf16(v1);
      }
      if constexpr (POOL) {
        float vs = v0 + v1;
#pragma unroll
        for (int m = 1; m <= 16; m <<= 1) vs += __shfl_xor(vs, m, 64);
        if (l31 == 0) Ps[wm * 128 + rloc] = vs;
      }
    }
  }
  if constexpr (POOL) {
    __syncthreads();
    if (tid < 128) {
      int row = rowBlock + tid;
      if (row < nrows) pool_out[row] = Ps[tid] + Ps[128 + tid];
    }
  }
}

// ---------------------------------------------------------------------------
// Workspace layout (bytes)
// ---------------------------------------------------------------------------
static constexpr size_t OFF_X    = 0;                          // N*128*2
static constexpr size_t OFF_E    = 5120000;                    // E*128*2
static constexpr size_t OFF_AGG  = 87040000;                   // N*128*2 (bf16)
static constexpr size_t OFF_PN1  = 92160000;                   // 65536
static constexpr size_t OFF_PN2  = OFF_PN1 + 65536;
static constexpr size_t OFF_PE1  = OFF_PN2 + 65536;
static constexpr size_t OFF_PE2  = OFF_PE1 + 65536;
static constexpr size_t OFF_PD1  = OFF_PE2 + 65536;            // 196608
static constexpr size_t OFF_PD2  = OFF_PD1 + 196608;
static constexpr size_t OFF_PM1  = OFF_PD2 + 65536;            // 131072
static constexpr size_t OFF_PM2  = OFF_PM1 + 131072;
static constexpr size_t OFF_CNT  = OFF_PM2 + 65536;            // N*4
static constexpr size_t OFF_OFFS = OFF_CNT + 80000;            // (N+1)*4
static constexpr size_t OFF_CUR  = OFF_OFFS + 80004;           // N*4
static constexpr size_t OFF_EID  = OFF_CUR + 80000;            // E*4

extern "C" void kernel_launch(void* const* d_in, const int* in_sizes, int n_in,
                              void* d_out, int out_size, void* d_ws, size_t ws_size,
                              hipStream_t stream) {
  const float* nodes = (const float*)d_in[0];
  const float* edges = (const float*)d_in[1];
  const int* senders = (const int*)d_in[2];
  const int* receivers = (const int*)d_in[3];
  const float* Wn1 = (const float*)d_in[4];  const float* bn1 = (const float*)d_in[5];
  const float* Wn2 = (const float*)d_in[6];  const float* bn2 = (const float*)d_in[7];
  const float* We1 = (const float*)d_in[8];  const float* be1 = (const float*)d_in[9];
  const float* We2 = (const float*)d_in[10]; const float* be2 = (const float*)d_in[11];
  const float* Wed1 = (const float*)d_in[12]; const float* bed1 = (const float*)d_in[13];
  const float* Wed2 = (const float*)d_in[14]; const float* bed2 = (const float*)d_in[15];
  const float* Wnd1 = (const float*)d_in[16]; const float* bnd1 = (const float*)d_in[17];
  const float* Wnd2 = (const float*)d_in[18]; const float* bnd2 = (const float*)d_in[19];

  char* ws = (char*)d_ws;
  unsigned short* xb   = (unsigned short*)(ws + OFF_X);
  unsigned short* eb   = (unsigned short*)(ws + OFF_E);
  unsigned short* aggb = (unsigned short*)(ws + OFF_AGG);
  unsigned short* Pn1  = (unsigned short*)(ws + OFF_PN1);
  unsigned short* Pn2  = (unsigned short*)(ws + OFF_PN2);
  unsigned short* Pe1  = (unsigned short*)(ws + OFF_PE1);
  unsigned short* Pe2  = (unsigned short*)(ws + OFF_PE2);
  unsigned short* Pd1  = (unsigned short*)(ws + OFF_PD1);
  unsigned short* Pd2  = (unsigned short*)(ws + OFF_PD2);
  unsigned short* Pm1  = (unsigned short*)(ws + OFF_PM1);
  unsigned short* Pm2  = (unsigned short*)(ws + OFF_PM2);
  int* cnt    = (int*)(ws + OFF_CNT);
  int* offs   = (int*)(ws + OFF_OFFS);
  int* cursor = (int*)(ws + OFF_CUR);
  int* eid    = (int*)(ws + OFF_EID);
  float* outp = (float*)d_out;

  // pack all 8 weight matrices into MFMA fragment order (bf16)
  pack_w<<<128, 256, 0, stream>>>(Wn1, Pn1, 128, 256);
  pack_w<<<128, 256, 0, stream>>>(Wn2, Pn2, 256, 128);
  pack_w<<<128, 256, 0, stream>>>(We1, Pe1, 128, 256);
  pack_w<<<128, 256, 0, stream>>>(We2, Pe2, 256, 128);
  pack_w<<<384, 256, 0, stream>>>(Wed1, Pd1, 384, 256);
  pack_w<<<128, 256, 0, stream>>>(Wed2, Pd2, 256, 128);
  pack_w<<<256, 256, 0, stream>>>(Wnd1, Pm1, 256, 256);
  pack_w<<<128, 256, 0, stream>>>(Wnd2, Pm2, 256, 128);

  // CSR for segment_sum over receivers
  hipMemsetAsync(cnt, 0, (size_t)N_NODES * 4, stream);
  hist_k<<<1250, 256, 0, stream>>>(receivers, cnt, N_EDGES);
  scan_k<<<1, 1024, 0, stream>>>(cnt, offs, cursor, N_NODES);
  fill_k<<<1250, 256, 0, stream>>>(receivers, cursor, eid, N_EDGES);

  const int nodeBlocks = (N_NODES + 127) / 128;  // 157
  const int edgeBlocks = N_EDGES / 128;          // 2500

  // embed stage
  mlp_kernel<128, 0, 0><<<nodeBlocks, 256, 0, stream>>>(
      nodes, nullptr, nullptr, nullptr, nullptr, nullptr,
      Pn1, bn1, Pn2, bn2, xb, nullptr, N_NODES);
  mlp_kernel<128, 0, 0><<<edgeBlocks, 256, 0, stream>>>(
      edges, nullptr, nullptr, nullptr, nullptr, nullptr,
      Pe1, be1, Pe2, be2, eb, nullptr, N_EDGES);

  for (int it = 0; it < 2; ++it) {
    mlp_kernel<384, 1, 0><<<edgeBlocks, 256, 0, stream>>>(
        nullptr, xb, eb, nullptr, senders, receivers,
        Pd1, bed1, Pd2, bed2, eb, nullptr, N_EDGES);
    agg_k<<<(N_NODES + 3) / 4, 256, 0, stream>>>(eb, offs, eid, aggb, N_NODES);
    mlp_kernel<256, 2, 1><<<nodeBlocks, 256, 0, stream>>>(
        nullptr, xb, nullptr, aggb, nullptr, nullptr,
        Pm1, bnd1, Pm2, bnd2, xb, outp + (size_t)it * N_NODES, N_NODES);
  }
}

// Round 6
// 526.478 us; speedup vs baseline: 1.3649x; 1.3649x over previous
//
#include <hip/hip_runtime.h>
#include <stdint.h>

#define N_NODES 20000
#define N_EDGES 320000

typedef __attribute__((ext_vector_type(8)))  __bf16        bf16x8;
typedef __attribute__((ext_vector_type(16))) float         f32x16;
typedef __attribute__((ext_vector_type(4)))  float         f32x4v;
typedef __attribute__((ext_vector_type(4)))  uint32_t      u32x4;
typedef __attribute__((ext_vector_type(8)))  unsigned short us8;
typedef __attribute__((ext_vector_type(2)))  unsigned short us2;

static __device__ __forceinline__ unsigned short cvt_bf16(float f) {
  uint32_t u = __builtin_bit_cast(uint32_t, f);
  u = (u + 0x7fffu + ((u >> 16) & 1u)) >> 16;
  return (unsigned short)u;
}
static __device__ __forceinline__ float cvt_f32(unsigned short h) {
  uint32_t u = ((uint32_t)h) << 16;
  return __builtin_bit_cast(float, u);
}

// async global->LDS, 16B per lane; LDS dest = wave-uniform base (HW adds lane*16)
static __device__ __forceinline__ void gll16(const void* g, void* l) {
  __builtin_amdgcn_global_load_lds(
      (const __attribute__((address_space(1))) unsigned int*)g,
      (__attribute__((address_space(3))) unsigned int*)l, 16, 0, 0);
}

// ---------------------------------------------------------------------------
// pack_w: natural k-order fragments (verified R1-R5). For W1 (A-operand of
// flipped L1):  out[((ks*(N/32)+nt)*64+ln)*8+e] = W[ks*16+(ln>>5)*8+e][nt*32+(ln&31)]
// ---------------------------------------------------------------------------
__global__ void pack_w(const float* __restrict__ W, unsigned short* __restrict__ out,
                       int K, int Ncols) {
  int idx = blockIdx.x * 256 + threadIdx.x;
  int total = K * Ncols;
  if (idx >= total) return;
  int e    = idx & 7;
  int lane = (idx >> 3) & 63;
  int t    = idx >> 9;
  int ntiles = Ncols >> 5;
  int nt = t % ntiles;
  int ks = t / ntiles;
  int k = ks * 16 + (lane >> 5) * 8 + e;
  int c = nt * 32 + (lane & 31);
  out[idx] = cvt_bf16(W[(size_t)k * Ncols + c]);
}

// ---------------------------------------------------------------------------
// pack_w2: sigma k-order for the register-resident H handoff.
// sigma(ks,g,e) = ks*16 + g*4 + (e&3) + 8*(e>>2)  (bijective per 16-k block)
// K=256, Ncols=128 for all our W2 matrices.
// ---------------------------------------------------------------------------
__global__ void pack_w2(const float* __restrict__ W, unsigned short* __restrict__ out) {
  int idx = blockIdx.x * 256 + threadIdx.x;     // 32768 total
  if (idx >= 32768) return;
  int e    = idx & 7;
  int lane = (idx >> 3) & 63;
  int t    = idx >> 9;          // frag = ks*4 + nt
  int nt = t & 3, ks = t >> 2;
  int k = ks * 16 + ((lane >> 5) << 2) + (e & 3) + ((e >> 2) << 3);
  int c = nt * 32 + (lane & 31);
  out[idx] = cvt_bf16(W[(size_t)k * 128 + c]);
}

// ---------------------------------------------------------------------------
// CSR build for segment_sum (receivers constant across iterations)
// ---------------------------------------------------------------------------
__global__ void hist_k(const int* __restrict__ recv, int* __restrict__ cnt, int n) {
  int i = blockIdx.x * 256 + threadIdx.x;
  if (i < n) atomicAdd(&cnt[recv[i]], 1);
}

__global__ void scan_k(const int* __restrict__ cnt, int* __restrict__ off,
                       int* __restrict__ cursor, int n) {
  __shared__ int part[1024];
  int t = threadIdx.x;
  int chunk = (n + 1023) / 1024;
  int base = t * chunk;
  int s = 0;
  for (int i = 0; i < chunk; ++i) { int idx = base + i; if (idx < n) s += cnt[idx]; }
  part[t] = s;
  __syncthreads();
  for (int d = 1; d < 1024; d <<= 1) {
    int v = (t >= d) ? part[t - d] : 0;
    __syncthreads();
    part[t] += v;
    __syncthreads();
  }
  int prefix = (t > 0) ? part[t - 1] : 0;
  for (int i = 0; i < chunk; ++i) {
    int idx = base + i;
    if (idx < n) { off[idx] = prefix; cursor[idx] = prefix; prefix += cnt[idx]; }
  }
  if (t == 1023) off[n] = part[1023];
}

__global__ void fill_k(const int* __restrict__ recv, int* __restrict__ cursor,
                       int* __restrict__ eid, int n) {
  int i = blockIdx.x * 256 + threadIdx.x;
  if (i < n) {
    int p = atomicAdd(&cursor[recv[i]], 1);
    eid[p] = i;
  }
}

// agg[n][:] = sum_{edges -> n} e[edge][:], f32 accumulate, bf16 out
__global__ void agg_k(const unsigned short* __restrict__ eb, const int* __restrict__ off,
                      const int* __restrict__ eid, unsigned short* __restrict__ aggb, int n) {
  int node = blockIdx.x * 4 + (threadIdx.x >> 6);
  if (node >= n) return;
  int lane = threadIdx.x & 63;
  float a0 = 0.f, a1 = 0.f;
  int s = off[node], t = off[node + 1];
  for (int q = s; q < t; ++q) {
    int ei = eid[q];
    us2 v = *(const us2*)(eb + (size_t)ei * 128 + lane * 2);
    a0 += cvt_f32(v[0]);
    a1 += cvt_f32(v[1]);
  }
  us2 r; r[0] = cvt_bf16(a0); r[1] = cvt_bf16(a1);
  *(us2*)(aggb + (size_t)node * 128 + lane * 2) = r;
}

// ---------------------------------------------------------------------------
// Fused 2-layer MLP: out = relu(relu(A@W1+b1)@W2+b2), hidden 256, out 128.
// 128 rows/block, 4 waves; wave-tile = FULL 256 hidden x 32 rows.
//   MODE 0: A = srcf (f32, per-lane direct loads)
//   MODE 1: A = [x[snd], x[rcv], e] bf16 (KIN=384, per-lane gather to regs)
//   MODE 2: A = [x, agg]            bf16 (KIN=256)
// L1 flipped (D1^T = W1f @ rows^T): acc1[8] tiles = 256 hid for 32 rows.
// H handoff IN REGISTERS via sigma k-order (pack_w2) -> L2 has NO LDS, NO
// barriers. LDS only = W1 dbuf 2x16KB, counted-vmcnt 2-phase (never drains
// mid-loop). W2 frags read direct from global (L2-cache-hot, shared by all).
// ---------------------------------------------------------------------------
template <int KIN, int MODE, int POOL>
__global__ __launch_bounds__(256, 2)
void mlp_kernel(const float* __restrict__ srcf,
                const unsigned short* __restrict__ xb,
                const unsigned short* __restrict__ ebuf,
                const unsigned short* __restrict__ aggb,
                const int* __restrict__ senders,
                const int* __restrict__ receivers,
                const unsigned short* __restrict__ P1,
                const float* __restrict__ b1,
                const unsigned short* __restrict__ P2,
                const float* __restrict__ b2,
                unsigned short* __restrict__ dst,
                float* __restrict__ pool_out,
                int nrows) {
  constexpr int NS1 = KIN / 32;                 // 4 / 12 / 8 (always even)
  __shared__ __align__(16) unsigned char lds[32768];   // W1 dbuf 2x16KB

  const int tid  = threadIdx.x;
  const int lane = tid & 63;
  const int wid  = tid >> 6;     // 0..3
  const int g    = lane >> 5;
  const int l31  = lane & 31;
  const int rowBlock = blockIdx.x << 7;

  const unsigned char* P1b = (const unsigned char*)P1;

  // this lane's row (wave w owns rows w*32..+32; lane l31 = row within)
  int grow = rowBlock + wid * 32 + l31;
  if (grow >= nrows) grow = nrows - 1;

  const unsigned short *pS = nullptr, *pR = nullptr, *pE = nullptr;
  const unsigned short *pX = nullptr, *pAg = nullptr;
  const float* fb = nullptr;
  if constexpr (MODE == 0) {
    fb = srcf + (size_t)grow * KIN;
  } else if constexpr (MODE == 1) {
    pS = xb + (size_t)senders[grow] * 128;
    pR = xb + (size_t)receivers[grow] * 128;
    pE = ebuf + (size_t)grow * 128;
  } else {
    pX  = xb + (size_t)grow * 128;
    pAg = aggb + (size_t)grow * 128;
  }

  // stage W1 chunk for k-step s into buf (s&1): 16KB, 4 gll/thread
  auto STG1 = [&](int s) {
    unsigned char* bW = lds + (s & 1) * 16384;
#pragma unroll
    for (int c = 0; c < 4; ++c)
      gll16(P1b + (size_t)s * 16384 + c * 4096 + tid * 16,
            bW + c * 4096 + wid * 1024);
  };

  // per-lane row fragment loads for k-step s (2 x us8, natural k-order)
  auto LROW = [&](int s, us8& o0, us8& o1) {
    const int k0s = s * 32;
    const unsigned short* p;
    if constexpr (MODE == 1) {
      const int seg = k0s >> 7;
      p = (seg == 0) ? pS : (seg == 1) ? pR : pE;
    } else {
      p = (k0s >> 7) ? pAg : pX;
    }
    const int ko = k0s & 127;
    o0 = *(const us8*)(p + ko + g * 8);
    o1 = *(const us8*)(p + ko + 16 + g * 8);
  };
  auto LROWF = [&](int s, f32x4v* rf) {
    const float* p = fb + s * 32 + g * 8;
    rf[0] = *(const f32x4v*)(p);
    rf[1] = *(const f32x4v*)(p + 4);
    rf[2] = *(const f32x4v*)(p + 16);
    rf[3] = *(const f32x4v*)(p + 20);
  };
  auto MKBR = [&](const f32x4v* rf, bf16x8& b0v, bf16x8& b1v) {
    us8 h0, h1;
#pragma unroll
    for (int e = 0; e < 4; ++e) {
      h0[e] = cvt_bf16(rf[0][e]); h0[4 + e] = cvt_bf16(rf[1][e]);
      h1[e] = cvt_bf16(rf[2][e]); h1[4 + e] = cvt_bf16(rf[3][e]);
    }
    b0v = __builtin_bit_cast(bf16x8, h0);
    b1v = __builtin_bit_cast(bf16x8, h1);
  };

  // ================= layer 1 =================
  f32x16 acc1[8];
#pragma unroll
  for (int t = 0; t < 8; ++t)
#pragma unroll
    for (int k = 0; k < 16; ++k) acc1[t][k] = 0.0f;

  auto COMPUTE = [&](const unsigned char* bW, bf16x8 b0v, bf16x8 b1v) {
#pragma unroll
    for (int kc = 0; kc < 2; ++kc) {
      const bf16x8 bv = kc ? b1v : b0v;
#pragma unroll
      for (int nt = 0; nt < 8; ++nt) {
        bf16x8 av = __builtin_bit_cast(bf16x8,
            *(const us8*)(bW + (kc * 8 + nt) * 1024 + lane * 16));
        acc1[nt] = __builtin_amdgcn_mfma_f32_32x32x16_bf16(av, bv, acc1[nt], 0, 0, 0);
      }
    }
  };

  constexpr int CNT = (MODE == 0) ? 8 : 6;   // in-flight: 4 gll + row loads

  us8 rA0, rA1, rB0, rB1;
  f32x4v rfA[4], rfB[4];

  STG1(0);
  if constexpr (MODE == 0) LROWF(0, rfA); else LROW(0, rA0, rA1);

#pragma unroll 1
  for (int s = 0; s < NS1; s += 2) {
    // ---- even step s: data {buf0, A}; stage s+1 into {buf1, B} ----
    STG1(s + 1);
    if constexpr (MODE == 0) LROWF(s + 1, rfB); else LROW(s + 1, rB0, rB1);
    asm volatile("s_waitcnt vmcnt(%0)" :: "i"(CNT) : "memory");
    asm volatile("s_barrier" ::: "memory");
    {
      bf16x8 b0v, b1v;
      if constexpr (MODE == 0) MKBR(rfA, b0v, b1v);
      else { b0v = __builtin_bit_cast(bf16x8, rA0); b1v = __builtin_bit_cast(bf16x8, rA1); }
      COMPUTE(lds, b0v, b1v);
    }
    asm volatile("s_waitcnt lgkmcnt(0)" ::: "memory");
    asm volatile("s_barrier" ::: "memory");

    // ---- odd step s+1: data {buf1, B}; stage s+2 into {buf0, A} ----
    const bool more = (s + 2 < NS1);
    if (more) {
      STG1(s + 2);
      if constexpr (MODE == 0) LROWF(s + 2, rfA); else LROW(s + 2, rA0, rA1);
      asm volatile("s_waitcnt vmcnt(%0)" :: "i"(CNT) : "memory");
    } else {
      asm volatile("s_waitcnt vmcnt(0)" ::: "memory");
    }
    asm volatile("s_barrier" ::: "memory");
    {
      bf16x8 b0v, b1v;
      if constexpr (MODE == 0) MKBR(rfB, b0v, b1v);
      else { b0v = __builtin_bit_cast(bf16x8, rB0); b1v = __builtin_bit_cast(bf16x8, rB1); }
      COMPUTE(lds + 16384, b0v, b1v);
    }
    if (more) {
      asm volatile("s_waitcnt lgkmcnt(0)" ::: "memory");
      asm volatile("s_barrier" ::: "memory");
    }
  }

  // ===== epilogue 1: bias+relu+cvt -> sigma-order A-frags, all in registers =====
  // hid(t,r,g) = t*32 + (r&3) + 8*(r>>2) + 4g ; frag(ks) = regs[8*(ks&1)..+8]
  u32x4 pa4[16];
#pragma unroll
  for (int t = 0; t < 8; ++t) {
#pragma unroll
    for (int q4 = 0; q4 < 4; ++q4) {
      const f32x4v bb = *(const f32x4v*)(b1 + t * 32 + q4 * 8 + g * 4);
      float v0 = fmaxf(acc1[t][q4 * 4 + 0] + bb[0], 0.0f);
      float v1 = fmaxf(acc1[t][q4 * 4 + 1] + bb[1], 0.0f);
      float v2 = fmaxf(acc1[t][q4 * 4 + 2] + bb[2], 0.0f);
      float v3 = fmaxf(acc1[t][q4 * 4 + 3] + bb[3], 0.0f);
      uint32_t lo, hi;
      asm("v_cvt_pk_bf16_f32 %0, %1, %2" : "=v"(lo) : "v"(v0), "v"(v1));
      asm("v_cvt_pk_bf16_f32 %0, %1, %2" : "=v"(hi) : "v"(v2), "v"(v3));
      pa4[t * 2 + (q4 >> 1)][(q4 & 1) * 2 + 0] = lo;
      pa4[t * 2 + (q4 >> 1)][(q4 & 1) * 2 + 1] = hi;
    }
  }

  // ================= layer 2: zero LDS, zero barriers =================
  f32x16 acc2[4];
#pragma unroll
  for (int nt = 0; nt < 4; ++nt)
#pragma unroll
    for (int k = 0; k < 16; ++k) acc2[nt][k] = 0.0f;

#pragma unroll
  for (int ks = 0; ks < 16; ++ks) {
    const bf16x8 a2 = __builtin_bit_cast(bf16x8, pa4[ks]);
#pragma unroll
    for (int nt = 0; nt < 4; ++nt) {
      const bf16x8 bw = __builtin_bit_cast(bf16x8,
          *(const us8*)(P2 + (size_t)((ks * 4 + nt) * 64 + lane) * 8));
      acc2[nt] = __builtin_amdgcn_mfma_f32_32x32x16_bf16(a2, bw, acc2[nt], 0, 0, 0);
    }
  }

  // ===== epilogue 2: bias+relu, coalesced bf16 stores, fused pool =====
  float bias2[4];
#pragma unroll
  for (int nt = 0; nt < 4; ++nt) bias2[nt] = b2[nt * 32 + l31];

#pragma unroll
  for (int reg = 0; reg < 16; ++reg) {
    const int rowpat = (reg & 3) + ((reg >> 2) << 3) + g * 4;
    const int row = rowBlock + wid * 32 + rowpat;
    float vs = 0.0f;
#pragma unroll
    for (int nt = 0; nt < 4; ++nt) {
      float v = fmaxf(acc2[nt][reg] + bias2[nt], 0.0f);
      vs += v;
      if (row < nrows) dst[(size_t)row * 128 + nt * 32 + l31] = cvt_bf16(v);
    }
    if constexpr (POOL) {
#pragma unroll
      for (int m = 1; m <= 16; m <<= 1) vs += __shfl_xor(vs, m, 64);
      if (l31 == 0 && row < nrows) pool_out[row] = vs;
    }
  }
}

// ---------------------------------------------------------------------------
// Workspace layout (bytes)
// ---------------------------------------------------------------------------
static constexpr size_t OFF_X    = 0;                          // N*128*2
static constexpr size_t OFF_E    = 5120000;                    // E*128*2
static constexpr size_t OFF_AGG  = 87040000;                   // N*128*2 (bf16)
static constexpr size_t OFF_PN1  = 92160000;                   // 65536
static constexpr size_t OFF_PN2  = OFF_PN1 + 65536;
static constexpr size_t OFF_PE1  = OFF_PN2 + 65536;
static constexpr size_t OFF_PE2  = OFF_PE1 + 65536;
static constexpr size_t OFF_PD1  = OFF_PE2 + 65536;            // 196608
static constexpr size_t OFF_PD2  = OFF_PD1 + 196608;
static constexpr size_t OFF_PM1  = OFF_PD2 + 65536;            // 131072
static constexpr size_t OFF_PM2  = OFF_PM1 + 131072;
static constexpr size_t OFF_CNT  = OFF_PM2 + 65536;            // N*4
static constexpr size_t OFF_OFFS = OFF_CNT + 80000;            // (N+1)*4
static constexpr size_t OFF_CUR  = OFF_OFFS + 80004;           // N*4
static constexpr size_t OFF_EID  = OFF_CUR + 80000;            // E*4

extern "C" void kernel_launch(void* const* d_in, const int* in_sizes, int n_in,
                              void* d_out, int out_size, void* d_ws, size_t ws_size,
                              hipStream_t stream) {
  const float* nodes = (const float*)d_in[0];
  const float* edges = (const float*)d_in[1];
  const int* senders = (const int*)d_in[2];
  const int* receivers = (const int*)d_in[3];
  const float* Wn1 = (const float*)d_in[4];  const float* bn1 = (const float*)d_in[5];
  const float* Wn2 = (const float*)d_in[6];  const float* bn2 = (const float*)d_in[7];
  const float* We1 = (const float*)d_in[8];  const float* be1 = (const float*)d_in[9];
  const float* We2 = (const float*)d_in[10]; const float* be2 = (const float*)d_in[11];
  const float* Wed1 = (const float*)d_in[12]; const float* bed1 = (const float*)d_in[13];
  const float* Wed2 = (const float*)d_in[14]; const float* bed2 = (const float*)d_in[15];
  const float* Wnd1 = (const float*)d_in[16]; const float* bnd1 = (const float*)d_in[17];
  const float* Wnd2 = (const float*)d_in[18]; const float* bnd2 = (const float*)d_in[19];

  char* ws = (char*)d_ws;
  unsigned short* xb   = (unsigned short*)(ws + OFF_X);
  unsigned short* eb   = (unsigned short*)(ws + OFF_E);
  unsigned short* aggb = (unsigned short*)(ws + OFF_AGG);
  unsigned short* Pn1  = (unsigned short*)(ws + OFF_PN1);
  unsigned short* Pn2  = (unsigned short*)(ws + OFF_PN2);
  unsigned short* Pe1  = (unsigned short*)(ws + OFF_PE1);
  unsigned short* Pe2  = (unsigned short*)(ws + OFF_PE2);
  unsigned short* Pd1  = (unsigned short*)(ws + OFF_PD1);
  unsigned short* Pd2  = (unsigned short*)(ws + OFF_PD2);
  unsigned short* Pm1  = (unsigned short*)(ws + OFF_PM1);
  unsigned short* Pm2  = (unsigned short*)(ws + OFF_PM2);
  int* cnt    = (int*)(ws + OFF_CNT);
  int* offs   = (int*)(ws + OFF_OFFS);
  int* cursor = (int*)(ws + OFF_CUR);
  int* eid    = (int*)(ws + OFF_EID);
  float* outp = (float*)d_out;

  // W1 matrices: natural k-order; W2 matrices: sigma k-order (all 256x128)
  pack_w<<<128, 256, 0, stream>>>(Wn1, Pn1, 128, 256);
  pack_w2<<<128, 256, 0, stream>>>(Wn2, Pn2);
  pack_w<<<128, 256, 0, stream>>>(We1, Pe1, 128, 256);
  pack_w2<<<128, 256, 0, stream>>>(We2, Pe2);
  pack_w<<<384, 256, 0, stream>>>(Wed1, Pd1, 384, 256);
  pack_w2<<<128, 256, 0, stream>>>(Wed2, Pd2);
  pack_w<<<256, 256, 0, stream>>>(Wnd1, Pm1, 256, 256);
  pack_w2<<<128, 256, 0, stream>>>(Wnd2, Pm2);

  // CSR for segment_sum over receivers
  hipMemsetAsync(cnt, 0, (size_t)N_NODES * 4, stream);
  hist_k<<<1250, 256, 0, stream>>>(receivers, cnt, N_EDGES);
  scan_k<<<1, 1024, 0, stream>>>(cnt, offs, cursor, N_NODES);
  fill_k<<<1250, 256, 0, stream>>>(receivers, cursor, eid, N_EDGES);

  const int nodeBlocks = (N_NODES + 127) / 128;  // 157
  const int edgeBlocks = N_EDGES / 128;          // 2500

  // embed stage
  mlp_kernel<128, 0, 0><<<nodeBlocks, 256, 0, stream>>>(
      nodes, nullptr, nullptr, nullptr, nullptr, nullptr,
      Pn1, bn1, Pn2, bn2, xb, nullptr, N_NODES);
  mlp_kernel<128, 0, 0><<<edgeBlocks, 256, 0, stream>>>(
      edges, nullptr, nullptr, nullptr, nullptr, nullptr,
      Pe1, be1, Pe2, be2, eb, nullptr, N_EDGES);

  for (int it = 0; it < 2; ++it) {
    mlp_kernel<384, 1, 0><<<edgeBlocks, 256, 0, stream>>>(
        nullptr, xb, eb, nullptr, senders, receivers,
        Pd1, bed1, Pd2, bed2, eb, nullptr, N_EDGES);
    agg_k<<<(N_NODES + 3) / 4, 256, 0, stream>>>(eb, offs, eid, aggb, N_NODES);
    mlp_kernel<256, 2, 1><<<nodeBlocks, 256, 0, stream>>>(
        nullptr, xb, nullptr, aggb, nullptr, nullptr,
        Pm1, bnd1, Pm2, bnd2, xb, outp + (size_t)it * N_NODES, N_NODES);
  }
}

// Round 7
// 515.482 us; speedup vs baseline: 1.3940x; 1.0213x over previous
//
#include <hip/hip_runtime.h>
#include <stdint.h>

#define N_NODES 20000
#define N_EDGES 320000

typedef __attribute__((ext_vector_type(8)))  __bf16        bf16x8;
typedef __attribute__((ext_vector_type(16))) float         f32x16;
typedef __attribute__((ext_vector_type(4)))  float         f32x4v;
typedef __attribute__((ext_vector_type(4)))  uint32_t      u32x4;
typedef __attribute__((ext_vector_type(8)))  unsigned short us8;
typedef __attribute__((ext_vector_type(2)))  unsigned short us2;

static __device__ __forceinline__ unsigned short cvt_bf16(float f) {
  uint32_t u = __builtin_bit_cast(uint32_t, f);
  u = (u + 0x7fffu + ((u >> 16) & 1u)) >> 16;
  return (unsigned short)u;
}
static __device__ __forceinline__ float cvt_f32(unsigned short h) {
  uint32_t u = ((uint32_t)h) << 16;
  return __builtin_bit_cast(float, u);
}

// async global->LDS, 16B per lane; LDS dest = wave-uniform base (HW adds lane*16)
static __device__ __forceinline__ void gll16(const void* g, void* l) {
  __builtin_amdgcn_global_load_lds(
      (const __attribute__((address_space(1))) unsigned int*)g,
      (__attribute__((address_space(3))) unsigned int*)l, 16, 0, 0);
}

// ---------------------------------------------------------------------------
// pack_w: natural k-order fragments (verified R1-R6). For W1 (A-operand of
// flipped L1):  out[((ks*(N/32)+nt)*64+ln)*8+e] = W[ks*16+(ln>>5)*8+e][nt*32+(ln&31)]
// ---------------------------------------------------------------------------
__global__ void pack_w(const float* __restrict__ W, unsigned short* __restrict__ out,
                       int K, int Ncols) {
  int idx = blockIdx.x * 256 + threadIdx.x;
  int total = K * Ncols;
  if (idx >= total) return;
  int e    = idx & 7;
  int lane = (idx >> 3) & 63;
  int t    = idx >> 9;
  int ntiles = Ncols >> 5;
  int nt = t % ntiles;
  int ks = t / ntiles;
  int k = ks * 16 + (lane >> 5) * 8 + e;
  int c = nt * 32 + (lane & 31);
  out[idx] = cvt_bf16(W[(size_t)k * Ncols + c]);
}

// ---------------------------------------------------------------------------
// pack_w2: sigma k-order for the register-resident H handoff (verified R6).
// sigma(ks,g,e) = ks*16 + g*4 + (e&3) + 8*(e>>2)
// ---------------------------------------------------------------------------
__global__ void pack_w2(const float* __restrict__ W, unsigned short* __restrict__ out) {
  int idx = blockIdx.x * 256 + threadIdx.x;     // 32768 total
  if (idx >= 32768) return;
  int e    = idx & 7;
  int lane = (idx >> 3) & 63;
  int t    = idx >> 9;          // frag = ks*4 + nt
  int nt = t & 3, ks = t >> 2;
  int k = ks * 16 + ((lane >> 5) << 2) + (e & 3) + ((e >> 2) << 3);
  int c = nt * 32 + (lane & 31);
  out[idx] = cvt_bf16(W[(size_t)k * 128 + c]);
}

// ---------------------------------------------------------------------------
// CSR build for segment_sum (receivers constant across iterations)
// ---------------------------------------------------------------------------
__global__ void hist_k(const int* __restrict__ recv, int* __restrict__ cnt, int n) {
  int i = blockIdx.x * 256 + threadIdx.x;
  if (i < n) atomicAdd(&cnt[recv[i]], 1);
}

__global__ void scan_k(const int* __restrict__ cnt, int* __restrict__ off,
                       int* __restrict__ cursor, int n) {
  __shared__ int part[1024];
  int t = threadIdx.x;
  int chunk = (n + 1023) / 1024;
  int base = t * chunk;
  int s = 0;
  for (int i = 0; i < chunk; ++i) { int idx = base + i; if (idx < n) s += cnt[idx]; }
  part[t] = s;
  __syncthreads();
  for (int d = 1; d < 1024; d <<= 1) {
    int v = (t >= d) ? part[t - d] : 0;
    __syncthreads();
    part[t] += v;
    __syncthreads();
  }
  int prefix = (t > 0) ? part[t - 1] : 0;
  for (int i = 0; i < chunk; ++i) {
    int idx = base + i;
    if (idx < n) { off[idx] = prefix; cursor[idx] = prefix; prefix += cnt[idx]; }
  }
  if (t == 1023) off[n] = part[1023];
}

__global__ void fill_k(const int* __restrict__ recv, int* __restrict__ cursor,
                       int* __restrict__ eid, int n) {
  int i = blockIdx.x * 256 + threadIdx.x;
  if (i < n) {
    int p = atomicAdd(&cursor[recv[i]], 1);
    eid[p] = i;
  }
}

// agg[n][:] = sum_{edges -> n} e[edge][:], f32 accumulate, bf16 out
__global__ void agg_k(const unsigned short* __restrict__ eb, const int* __restrict__ off,
                      const int* __restrict__ eid, unsigned short* __restrict__ aggb, int n) {
  int node = blockIdx.x * 4 + (threadIdx.x >> 6);
  if (node >= n) return;
  int lane = threadIdx.x & 63;
  float a0 = 0.f, a1 = 0.f;
  int s = off[node], t = off[node + 1];
  for (int q = s; q < t; ++q) {
    int ei = eid[q];
    us2 v = *(const us2*)(eb + (size_t)ei * 128 + lane * 2);
    a0 += cvt_f32(v[0]);
    a1 += cvt_f32(v[1]);
  }
  us2 r; r[0] = cvt_bf16(a0); r[1] = cvt_bf16(a1);
  *(us2*)(aggb + (size_t)node * 128 + lane * 2) = r;
}

// ---------------------------------------------------------------------------
// Fused 2-layer MLP: out = relu(relu(A@W1+b1)@W2+b2), hidden 256, out 128.
// 128 rows/block, 4 waves; wave-tile = FULL 256 hidden x 32 rows.
// L1 flipped (D1^T = W1f @ rows^T); H handoff IN REGISTERS (sigma order).
// R7: W2 staged once/block through the dead W1-LDS region (4 x 16KB chunks,
// counted vmcnt, stage(c+2) only after post-compute barrier) -> W2 L2
// traffic /4. s_setprio(1) around MFMA clusters (2 independent blocks/CU).
// ---------------------------------------------------------------------------
template <int KIN, int MODE, int POOL>
__global__ __launch_bounds__(256, 2)
void mlp_kernel(const float* __restrict__ srcf,
                const unsigned short* __restrict__ xb,
                const unsigned short* __restrict__ ebuf,
                const unsigned short* __restrict__ aggb,
                const int* __restrict__ senders,
                const int* __restrict__ receivers,
                const unsigned short* __restrict__ P1,
                const float* __restrict__ b1,
                const unsigned short* __restrict__ P2,
                const float* __restrict__ b2,
                unsigned short* __restrict__ dst,
                float* __restrict__ pool_out,
                int nrows) {
  constexpr int NS1 = KIN / 32;                 // 4 / 12 / 8 (always even)
  __shared__ __align__(16) unsigned char lds[32768];   // W1 dbuf / W2 chunk dbuf

  const int tid  = threadIdx.x;
  const int lane = tid & 63;
  const int wid  = tid >> 6;     // 0..3
  const int g    = lane >> 5;
  const int l31  = lane & 31;
  const int rowBlock = blockIdx.x << 7;

  const unsigned char* P1b = (const unsigned char*)P1;
  const unsigned char* P2b = (const unsigned char*)P2;

  // this lane's row (wave w owns rows w*32..+32; lane l31 = row within)
  int grow = rowBlock + wid * 32 + l31;
  if (grow >= nrows) grow = nrows - 1;

  const unsigned short *pS = nullptr, *pR = nullptr, *pE = nullptr;
  const unsigned short *pX = nullptr, *pAg = nullptr;
  const float* fb = nullptr;
  if constexpr (MODE == 0) {
    fb = srcf + (size_t)grow * KIN;
  } else if constexpr (MODE == 1) {
    pS = xb + (size_t)senders[grow] * 128;
    pR = xb + (size_t)receivers[grow] * 128;
    pE = ebuf + (size_t)grow * 128;
  } else {
    pX  = xb + (size_t)grow * 128;
    pAg = aggb + (size_t)grow * 128;
  }

  // stage W1 chunk for k-step s into buf (s&1): 16KB, 4 gll/thread
  auto STG1 = [&](int s) {
    unsigned char* bW = lds + (s & 1) * 16384;
#pragma unroll
    for (int c = 0; c < 4; ++c)
      gll16(P1b + (size_t)s * 16384 + c * 4096 + tid * 16,
            bW + c * 4096 + wid * 1024);
  };
  // stage W2 chunk c (16KB = 4 ks-groups) into buf (c&1)
  auto STG2 = [&](int c) {
    unsigned char* bW = lds + (c & 1) * 16384;
#pragma unroll
    for (int q = 0; q < 4; ++q)
      gll16(P2b + (size_t)c * 16384 + q * 4096 + tid * 16,
            bW + q * 4096 + wid * 1024);
  };

  // per-lane row fragment loads for k-step s (2 x us8, natural k-order)
  auto LROW = [&](int s, us8& o0, us8& o1) {
    const int k0s = s * 32;
    const unsigned short* p;
    if constexpr (MODE == 1) {
      const int seg = k0s >> 7;
      p = (seg == 0) ? pS : (seg == 1) ? pR : pE;
    } else {
      p = (k0s >> 7) ? pAg : pX;
    }
    const int ko = k0s & 127;
    o0 = *(const us8*)(p + ko + g * 8);
    o1 = *(const us8*)(p + ko + 16 + g * 8);
  };
  auto LROWF = [&](int s, f32x4v* rf) {
    const float* p = fb + s * 32 + g * 8;
    rf[0] = *(const f32x4v*)(p);
    rf[1] = *(const f32x4v*)(p + 4);
    rf[2] = *(const f32x4v*)(p + 16);
    rf[3] = *(const f32x4v*)(p + 20);
  };
  auto MKBR = [&](const f32x4v* rf, bf16x8& b0v, bf16x8& b1v) {
    us8 h0, h1;
#pragma unroll
    for (int e = 0; e < 4; ++e) {
      h0[e] = cvt_bf16(rf[0][e]); h0[4 + e] = cvt_bf16(rf[1][e]);
      h1[e] = cvt_bf16(rf[2][e]); h1[4 + e] = cvt_bf16(rf[3][e]);
    }
    b0v = __builtin_bit_cast(bf16x8, h0);
    b1v = __builtin_bit_cast(bf16x8, h1);
  };

  // ================= layer 1 =================
  f32x16 acc1[8];
#pragma unroll
  for (int t = 0; t < 8; ++t)
#pragma unroll
    for (int k = 0; k < 16; ++k) acc1[t][k] = 0.0f;

  auto COMPUTE = [&](const unsigned char* bW, bf16x8 b0v, bf16x8 b1v) {
    __builtin_amdgcn_s_setprio(1);
#pragma unroll
    for (int kc = 0; kc < 2; ++kc) {
      const bf16x8 bv = kc ? b1v : b0v;
#pragma unroll
      for (int nt = 0; nt < 8; ++nt) {
        bf16x8 av = __builtin_bit_cast(bf16x8,
            *(const us8*)(bW + (kc * 8 + nt) * 1024 + lane * 16));
        acc1[nt] = __builtin_amdgcn_mfma_f32_32x32x16_bf16(av, bv, acc1[nt], 0, 0, 0);
      }
    }
    __builtin_amdgcn_s_setprio(0);
  };

  constexpr int CNT = (MODE == 0) ? 8 : 6;   // in-flight: 4 gll + row loads

  us8 rA0, rA1, rB0, rB1;
  f32x4v rfA[4], rfB[4];

  STG1(0);
  if constexpr (MODE == 0) LROWF(0, rfA); else LROW(0, rA0, rA1);

#pragma unroll 1
  for (int s = 0; s < NS1; s += 2) {
    // ---- even step s: data {buf0, A}; stage s+1 into {buf1, B} ----
    STG1(s + 1);
    if constexpr (MODE == 0) LROWF(s + 1, rfB); else LROW(s + 1, rB0, rB1);
    asm volatile("s_waitcnt vmcnt(%0)" :: "i"(CNT) : "memory");
    asm volatile("s_barrier" ::: "memory");
    {
      bf16x8 b0v, b1v;
      if constexpr (MODE == 0) MKBR(rfA, b0v, b1v);
      else { b0v = __builtin_bit_cast(bf16x8, rA0); b1v = __builtin_bit_cast(bf16x8, rA1); }
      COMPUTE(lds, b0v, b1v);
    }
    asm volatile("s_waitcnt lgkmcnt(0)" ::: "memory");
    asm volatile("s_barrier" ::: "memory");

    // ---- odd step s+1: data {buf1, B}; stage s+2 into {buf0, A} ----
    const bool more = (s + 2 < NS1);
    if (more) {
      STG1(s + 2);
      if constexpr (MODE == 0) LROWF(s + 2, rfA); else LROW(s + 2, rA0, rA1);
      asm volatile("s_waitcnt vmcnt(%0)" :: "i"(CNT) : "memory");
    } else {
      asm volatile("s_waitcnt vmcnt(0)" ::: "memory");
    }
    asm volatile("s_barrier" ::: "memory");
    {
      bf16x8 b0v, b1v;
      if constexpr (MODE == 0) MKBR(rfB, b0v, b1v);
      else { b0v = __builtin_bit_cast(bf16x8, rB0); b1v = __builtin_bit_cast(bf16x8, rB1); }
      COMPUTE(lds + 16384, b0v, b1v);
    }
    if (more) {
      asm volatile("s_waitcnt lgkmcnt(0)" ::: "memory");
      asm volatile("s_barrier" ::: "memory");
    }
  }
  // (last COMPUTE read buf1; buf0 safe to overwrite immediately)

  // ---- bias preload FIRST so vmcnt counting below stays exact ----
  f32x4v bb[8];
#pragma unroll
  for (int t = 0; t < 8; ++t)
    bb[t] = *(const f32x4v*)(b1 + t * 32 + (lane & 7) * 4);  // only need t*32+q4*8+g*4; reload below
  // NOTE: bb above is a warm-up touch; exact values loaded per-use below are L2-hot.

  STG2(0);                                   // -> buf0 (safe)
  asm volatile("s_waitcnt lgkmcnt(0)" ::: "memory");
  asm volatile("s_barrier" ::: "memory");    // all waves done reading buf1
  STG2(1);                                   // -> buf1

  // ===== epilogue 1: bias+relu+cvt -> sigma-order A-frags, in registers =====
  // hid(t,r,g) = t*32 + (r&3) + 8*(r>>2) + 4g ; frag(ks) = regs[8*(ks&1)..+8]
  u32x4 pa4[16];
#pragma unroll
  for (int t = 0; t < 8; ++t) {
#pragma unroll
    for (int q4 = 0; q4 < 4; ++q4) {
      const f32x4v bv4 = *(const f32x4v*)(b1 + t * 32 + q4 * 8 + g * 4);
      float v0 = fmaxf(acc1[t][q4 * 4 + 0] + bv4[0], 0.0f);
      float v1 = fmaxf(acc1[t][q4 * 4 + 1] + bv4[1], 0.0f);
      float v2 = fmaxf(acc1[t][q4 * 4 + 2] + bv4[2], 0.0f);
      float v3 = fmaxf(acc1[t][q4 * 4 + 3] + bv4[3], 0.0f);
      uint32_t lo, hi;
      asm("v_cvt_pk_bf16_f32 %0, %1, %2" : "=v"(lo) : "v"(v0), "v"(v1));
      asm("v_cvt_pk_bf16_f32 %0, %1, %2" : "=v"(hi) : "v"(v2), "v"(v3));
      pa4[t * 2 + (q4 >> 1)][(q4 & 1) * 2 + 0] = lo;
      pa4[t * 2 + (q4 >> 1)][(q4 & 1) * 2 + 1] = hi;
    }
  }

  // ================= layer 2: W2 from LDS chunks, counted pipeline =========
  f32x16 acc2[4];
#pragma unroll
  for (int nt = 0; nt < 4; ++nt)
#pragma unroll
    for (int k = 0; k < 16; ++k) acc2[nt][k] = 0.0f;

#pragma unroll
  for (int c = 0; c < 4; ++c) {
    if (c < 3) asm volatile("s_waitcnt vmcnt(4)" ::: "memory");
    else       asm volatile("s_waitcnt vmcnt(0)" ::: "memory");
    asm volatile("s_barrier" ::: "memory");
    const unsigned char* bW = lds + (c & 1) * 16384;
    __builtin_amdgcn_s_setprio(1);
#pragma unroll
    for (int kk = 0; kk < 4; ++kk) {
      const bf16x8 a2 = __builtin_bit_cast(bf16x8, pa4[c * 4 + kk]);
#pragma unroll
      for (int nt = 0; nt < 4; ++nt) {
        const bf16x8 bw = __builtin_bit_cast(bf16x8,
            *(const us8*)(bW + (kk * 4 + nt) * 1024 + lane * 16));
        acc2[nt] = __builtin_amdgcn_mfma_f32_32x32x16_bf16(a2, bw, acc2[nt], 0, 0, 0);
      }
    }
    __builtin_amdgcn_s_setprio(0);
    asm volatile("s_waitcnt lgkmcnt(0)" ::: "memory");
    asm volatile("s_barrier" ::: "memory");
    if (c + 2 < 4) STG2(c + 2);   // after barrier: buf (c&1) free to overwrite
  }

  // ===== epilogue 2: bias+relu, bf16 stores, fused pool =====
  float bias2[4];
#pragma unroll
  for (int nt = 0; nt < 4; ++nt) bias2[nt] = b2[nt * 32 + l31];

#pragma unroll
  for (int reg = 0; reg < 16; ++reg) {
    const int rowpat = (reg & 3) + ((reg >> 2) << 3) + g * 4;
    const int row = rowBlock + wid * 32 + rowpat;
    float vs = 0.0f;
#pragma unroll
    for (int nt = 0; nt < 4; ++nt) {
      float v = fmaxf(acc2[nt][reg] + bias2[nt], 0.0f);
      vs += v;
      if (row < nrows) dst[(size_t)row * 128 + nt * 32 + l31] = cvt_bf16(v);
    }
    if constexpr (POOL) {
#pragma unroll
      for (int m = 1; m <= 16; m <<= 1) vs += __shfl_xor(vs, m, 64);
      if (l31 == 0 && row < nrows) pool_out[row] = vs;
    }
  }
}

// ---------------------------------------------------------------------------
// Workspace layout (bytes)
// ---------------------------------------------------------------------------
static constexpr size_t OFF_X    = 0;                          // N*128*2
static constexpr size_t OFF_E    = 5120000;                    // E*128*2
static constexpr size_t OFF_AGG  = 87040000;                   // N*128*2 (bf16)
static constexpr size_t OFF_PN1  = 92160000;                   // 65536
static constexpr size_t OFF_PN2  = OFF_PN1 + 65536;
static constexpr size_t OFF_PE1  = OFF_PN2 + 65536;
static constexpr size_t OFF_PE2  = OFF_PE1 + 65536;
static constexpr size_t OFF_PD1  = OFF_PE2 + 65536;            // 196608
static constexpr size_t OFF_PD2  = OFF_PD1 + 196608;
static constexpr size_t OFF_PM1  = OFF_PD2 + 65536;            // 131072
static constexpr size_t OFF_PM2  = OFF_PM1 + 131072;
static constexpr size_t OFF_CNT  = OFF_PM2 + 65536;            // N*4
static constexpr size_t OFF_OFFS = OFF_CNT + 80000;            // (N+1)*4
static constexpr size_t OFF_CUR  = OFF_OFFS + 80004;           // N*4
static constexpr size_t OFF_EID  = OFF_CUR + 80000;            // E*4

extern "C" void kernel_launch(void* const* d_in, const int* in_sizes, int n_in,
                              void* d_out, int out_size, void* d_ws, size_t ws_size,
                              hipStream_t stream) {
  const float* nodes = (const float*)d_in[0];
  const float* edges = (const float*)d_in[1];
  const int* senders = (const int*)d_in[2];
  const int* receivers = (const int*)d_in[3];
  const float* Wn1 = (const float*)d_in[4];  const float* bn1 = (const float*)d_in[5];
  const float* Wn2 = (const float*)d_in[6];  const float* bn2 = (const float*)d_in[7];
  const float* We1 = (const float*)d_in[8];  const float* be1 = (const float*)d_in[9];
  const float* We2 = (const float*)d_in[10]; const float* be2 = (const float*)d_in[11];
  const float* Wed1 = (const float*)d_in[12]; const float* bed1 = (const float*)d_in[13];
  const float* Wed2 = (const float*)d_in[14]; const float* bed2 = (const float*)d_in[15];
  const float* Wnd1 = (const float*)d_in[16]; const float* bnd1 = (const float*)d_in[17];
  const float* Wnd2 = (const float*)d_in[18]; const float* bnd2 = (const float*)d_in[19];

  char* ws = (char*)d_ws;
  unsigned short* xb   = (unsigned short*)(ws + OFF_X);
  unsigned short* eb   = (unsigned short*)(ws + OFF_E);
  unsigned short* aggb = (unsigned short*)(ws + OFF_AGG);
  unsigned short* Pn1  = (unsigned short*)(ws + OFF_PN1);
  unsigned short* Pn2  = (unsigned short*)(ws + OFF_PN2);
  unsigned short* Pe1  = (unsigned short*)(ws + OFF_PE1);
  unsigned short* Pe2  = (unsigned short*)(ws + OFF_PE2);
  unsigned short* Pd1  = (unsigned short*)(ws + OFF_PD1);
  unsigned short* Pd2  = (unsigned short*)(ws + OFF_PD2);
  unsigned short* Pm1  = (unsigned short*)(ws + OFF_PM1);
  unsigned short* Pm2  = (unsigned short*)(ws + OFF_PM2);
  int* cnt    = (int*)(ws + OFF_CNT);
  int* offs   = (int*)(ws + OFF_OFFS);
  int* cursor = (int*)(ws + OFF_CUR);
  int* eid    = (int*)(ws + OFF_EID);
  float* outp = (float*)d_out;

  // W1 matrices: natural k-order; W2 matrices: sigma k-order (all 256x128)
  pack_w<<<128, 256, 0, stream>>>(Wn1, Pn1, 128, 256);
  pack_w2<<<128, 256, 0, stream>>>(Wn2, Pn2);
  pack_w<<<128, 256, 0, stream>>>(We1, Pe1, 128, 256);
  pack_w2<<<128, 256, 0, stream>>>(We2, Pe2);
  pack_w<<<384, 256, 0, stream>>>(Wed1, Pd1, 384, 256);
  pack_w2<<<128, 256, 0, stream>>>(Wed2, Pd2);
  pack_w<<<256, 256, 0, stream>>>(Wnd1, Pm1, 256, 256);
  pack_w2<<<128, 256, 0, stream>>>(Wnd2, Pm2);

  // CSR for segment_sum over receivers
  hipMemsetAsync(cnt, 0, (size_t)N_NODES * 4, stream);
  hist_k<<<1250, 256, 0, stream>>>(receivers, cnt, N_EDGES);
  scan_k<<<1, 1024, 0, stream>>>(cnt, offs, cursor, N_NODES);
  fill_k<<<1250, 256, 0, stream>>>(receivers, cursor, eid, N_EDGES);

  const int nodeBlocks = (N_NODES + 127) / 128;  // 157
  const int edgeBlocks = N_EDGES / 128;          // 2500

  // embed stage
  mlp_kernel<128, 0, 0><<<nodeBlocks, 256, 0, stream>>>(
      nodes, nullptr, nullptr, nullptr, nullptr, nullptr,
      Pn1, bn1, Pn2, bn2, xb, nullptr, N_NODES);
  mlp_kernel<128, 0, 0><<<edgeBlocks, 256, 0, stream>>>(
      edges, nullptr, nullptr, nullptr, nullptr, nullptr,
      Pe1, be1, Pe2, be2, eb, nullptr, N_EDGES);

  for (int it = 0; it < 2; ++it) {
    mlp_kernel<384, 1, 0><<<edgeBlocks, 256, 0, stream>>>(
        nullptr, xb, eb, nullptr, senders, receivers,
        Pd1, bed1, Pd2, bed2, eb, nullptr, N_EDGES);
    agg_k<<<(N_NODES + 3) / 4, 256, 0, stream>>>(eb, offs, eid, aggb, N_NODES);
    mlp_kernel<256, 2, 1><<<nodeBlocks, 256, 0, stream>>>(
        nullptr, xb, nullptr, aggb, nullptr, nullptr,
        Pm1, bnd1, Pm2, bnd2, xb, outp + (size_t)it * N_NODES, N_NODES);
  }
}